// Round 8
// baseline (48.019 us; speedup 1.0000x reference)
//
#include <hip/hip_runtime.h>
#include <math.h>

// Duhamel layer == per-channel causal FIR, h[q] = (1/wD) r^q sin(q*theta).
// Single-stream exact form: e[k] = (x[k] - g^W x[k-W])/wD; Z = g*Z + e[k];
// y[n] = Im(Z[n]).
// WAVE-AUTONOMOUS: each 64-lane wave produces 1024 outputs with no LDS and
// no barriers.  Lanes scan hseg halo samples each (H = 64*hseg) + 16 output
// samples; two intra-wave affine shfl-scans deliver exact per-lane seeds;
// correction Im(g^{j+1} seed) is fused into the coalesced-enough store.
// Grid = 8ch x 16batch x 16blocks x 256thr = 524,288 thr = exactly one full
// GPU pass at 8 waves/SIMD (requires VGPR <= 64 -> launch_bounds(256,8)).

#define N_SAMP  65536
#define NB      16
#define NO      8
#define NT      256
#define OW      1024     // output samples per wave
#define LSEG    16       // output samples per lane

// Static FIR lengths (exact replica of reference VALID_W):
constexpr int CW[NO]    = {1844, 1317, 1024, 768, 576, 419, 307, 230};
// Per-lane halo segment (mult of 4); H = 64*hseg gives alpha*H >= 7
// for every channel (seed truncation error <= e^-7, proven absmax 0.031).
constexpr int CHSEG[NO] = {44, 32, 28, 20, 16, 12, 8, 8};

__device__ __forceinline__ float rfl(float x) {
    return __int_as_float(__builtin_amdgcn_readfirstlane(__float_as_int(x)));
}

// Guarded aligned-quad load: g is a multiple of 4; negative g (whole quad
// below 0, since g % 4 == 0) returns zeros without faulting.
__device__ __forceinline__ float4 ldq0(const float* __restrict__ xb, int g) {
    const int ga = (g < 0) ? 0 : g;
    float4 q = *(const float4*)(xb + ga);
    if (g < 0) { q.x = 0.f; q.y = 0.f; q.z = 0.f; q.w = 0.f; }
    return q;
}

template<int O>
__device__ __forceinline__ void duh_run(const float* __restrict__ xg,
                                        const float* __restrict__ logw,
                                        float* __restrict__ out,
                                        int w, int b)
{
    constexpr int W   = CW[O];
    constexpr int HS  = CHSEG[O];
    constexpr int H   = 64 * HS;
    constexpr int QH  = HS / 4;
    constexpr int D   = (4 - (W & 3)) & 3;   // (-W) mod 4: aligned-quad shift

    const int t = threadIdx.x & 63;

    // ---- per-channel constants (fast HW transcendentals) -> SGPR ----------
    const float XIf = 0.05f, DTf = 0.01f;
    const float omf  = fminf(fmaxf(__expf(logw[O]), 0.01f), 1000.0f);
    const float omD  = omf * sqrtf(1.0f - XIf * XIf);
    const float th   = omD * DTf;
    const float alph = XIf * omf * DTf;

    const float r1 = __expf(-alph);
    const float gr = rfl(r1 * __cosf(th)), gi = rfl(r1 * __sinf(th));   // g

    const float rW   = __expf(-alph * (float)W);
    const float aW   = th * (float)W;
    const float binv = rfl(1.0f / omD);
    const float sWr  = rfl(rW * __cosf(aW));                 // Re g^W
    const float cei  = rfl(-binv * rW * __sinf(aW));         // -Im(g^W)/wD

    float Mhr[6], Mhi[6];                        // g^(HS*2^k) : halo scan
    {
        const float rl = __expf(-alph * (float)HS);
        const float al = th * (float)HS;
        float pr = rl * __cosf(al), pq = rl * __sinf(al);
#pragma unroll
        for (int k = 0; k < 6; ++k) {
            Mhr[k] = rfl(pr); Mhi[k] = rfl(pq);
            const float nr = pr * pr - pq * pq;
            const float ni = 2.0f * pr * pq;
            pr = nr; pq = ni;
        }
    }
    float Mor[6], Moi[6];                        // g^(16*2^k) : out scan + pl
    {
        const float rl = __expf(-alph * (float)LSEG);
        const float al = th * (float)LSEG;
        float pr = rl * __cosf(al), pq = rl * __sinf(al);
#pragma unroll
        for (int k = 0; k < 6; ++k) {
            Mor[k] = rfl(pr); Moi[k] = rfl(pq);
            const float nr = pr * pr - pq * pq;
            const float ni = 2.0f * pr * pq;
            pr = nr; pq = ni;
        }
    }

#define STEP(xa, xc)                                            \
    {                                                           \
        const float er = binv * fmaf(-sWr, (xc), (xa));         \
        const float ei = cei * (xc);                            \
        const float nr = fmaf(gr, Br, fmaf(-gi, Bi, er));       \
        const float ni = fmaf(gi, Br, fmaf( gr, Bi, ei));       \
        Br = nr; Bi = ni;                                       \
    }
#define DSEL(d0, d1, d2, d3, qc, qn)                                        \
    if constexpr (D == 0)      { d0 = qc.x; d1 = qc.y; d2 = qc.z; d3 = qc.w; } \
    else if constexpr (D == 1) { d0 = qc.y; d1 = qc.z; d2 = qc.w; d3 = qn.x; } \
    else if constexpr (D == 2) { d0 = qc.z; d1 = qc.w; d2 = qn.x; d3 = qn.y; } \
    else                       { d0 = qc.w; d1 = qn.x; d2 = qn.y; d3 = qn.z; }

    const float* xb = xg + (size_t)b * N_SAMP;
    const int n0w = w * OW;

    // ---------------- halo phase: hseg samples/lane, zero init --------------
    float Br = 0.f, Bi = 0.f;
    {
        const int hb = n0w - H + t * HS;       // mult of 4
        const int hd = hb - W - D;             // mult of 4
        float4 qc = ldq0(xb, hd);
#pragma unroll 2
        for (int m = 0; m < QH; ++m) {
            const float4 s1 = ldq0(xb, hb + 4 * m);
            const float4 qn = ldq0(xb, hd + 4 * (m + 1));
            float d0, d1, d2, d3;
            DSEL(d0, d1, d2, d3, qc, qn);
            STEP(s1.x, d0); STEP(s1.y, d1); STEP(s1.z, d2); STEP(s1.w, d3);
            qc = qn;
        }
    }

    // halo scan: inclusive affine over lanes, multiplier g^HS; lane63 = state
    // at n0w; broadcast it.
    float Sr = Br, Si = Bi;
#pragma unroll
    for (int k = 0; k < 6; ++k) {
        const int d = 1 << k;
        const float ur = __shfl_up(Sr, d, 64);
        const float ui = __shfl_up(Si, d, 64);
        if (t >= d) {
            const float nr = fmaf(Mhr[k], ur, fmaf(-Mhi[k], ui, Sr));
            const float ni = fmaf(Mhr[k], ui, fmaf( Mhi[k], ur, Si));
            Sr = nr; Si = ni;
        }
    }
    const float Tr = __shfl(Sr, 63, 64);
    const float Ti = __shfl(Si, 63, 64);

    // ---------------- output phase: 16 samples/lane, zero init, keep ly -----
    float ly[LSEG];
    Br = 0.f; Bi = 0.f;
    const int ob = n0w + t * LSEG;
    {
        const int od = ob - W - D;             // mult of 4
        float4 qc = ldq0(xb, od);
#pragma unroll
        for (int m = 0; m < 4; ++m) {
            const float4 s1 = ldq0(xb, ob + 4 * m);
            const float4 qn = ldq0(xb, od + 4 * (m + 1));
            float d0, d1, d2, d3;
            DSEL(d0, d1, d2, d3, qc, qn);
            STEP(s1.x, d0); ly[4 * m + 0] = Bi;
            STEP(s1.y, d1); ly[4 * m + 1] = Bi;
            STEP(s1.z, d2); ly[4 * m + 2] = Bi;
            STEP(s1.w, d3); ly[4 * m + 3] = Bi;
            qc = qn;
        }
    }

    // out scan: inclusive -> exclusive prefix of per-lane partials (mult g^16)
    float S2r = Br, S2i = Bi;
#pragma unroll
    for (int k = 0; k < 6; ++k) {
        const int d = 1 << k;
        const float ur = __shfl_up(S2r, d, 64);
        const float ui = __shfl_up(S2i, d, 64);
        if (t >= d) {
            const float nr = fmaf(Mor[k], ur, fmaf(-Moi[k], ui, S2r));
            const float ni = fmaf(Mor[k], ui, fmaf( Moi[k], ur, S2i));
            S2r = nr; S2i = ni;
        }
    }
    float exr = __shfl_up(S2r, 1, 64);
    float exi = __shfl_up(S2i, 1, 64);
    if (t == 0) { exr = 0.f; exi = 0.f; }

    // pl = g^(16*t) via bit-product of Mo
    float plr = 1.f, pli = 0.f;
#pragma unroll
    for (int k = 0; k < 6; ++k) {
        if ((t >> k) & 1) {
            const float nr = plr * Mor[k] - pli * Moi[k];
            const float ni = plr * Moi[k] + pli * Mor[k];
            plr = nr; pli = ni;
        }
    }
    // exact seed entering this lane's output segment: u = pl*T + excl
    const float sr = fmaf(plr, Tr, fmaf(-pli, Ti, exr));
    const float si = fmaf(plr, Ti, fmaf( pli, Tr, exi));

    // ---------------- fused correction + store ------------------------------
    // y[j] = ly[j] + Im(g^{j+1} * u), serial rotation v <- g*v.
    float vr = fmaf(gr, sr, -(gi * si));
    float vi = fmaf(gi, sr,  (gr * si));
    float* op = out + ((size_t)(b * NO + O)) * (size_t)N_SAMP + ob;
#pragma unroll
    for (int m = 0; m < 4; ++m) {
        float4 yq;
#pragma unroll
        for (int u = 0; u < 4; ++u) {
            ((float*)&yq)[u] = ly[4 * m + u] + vi;
            const float nr = fmaf(gr, vr, -(gi * vi));
            const float ni = fmaf(gi, vr,  (gr * vi));
            vr = nr; vi = ni;
        }
        *(float4*)(op + 4 * m) = yq;
    }
#undef STEP
#undef DSEL
}

__global__ __launch_bounds__(NT, 8)
void duh_kernel(const float* __restrict__ x, const float* __restrict__ logw,
                float* __restrict__ out)
{
    const int bid = blockIdx.x;
    const int o   = bid & 7;          // channel fastest -> per-CU channel mix
    const int r   = bid >> 3;
    const int b   = r & 15;
    const int w   = ((r >> 4) << 2) + (threadIdx.x >> 6);   // wave id 0..63
    if      (o == 0) duh_run<0>(x, logw, out, w, b);
    else if (o == 1) duh_run<1>(x, logw, out, w, b);
    else if (o == 2) duh_run<2>(x, logw, out, w, b);
    else if (o == 3) duh_run<3>(x, logw, out, w, b);
    else if (o == 4) duh_run<4>(x, logw, out, w, b);
    else if (o == 5) duh_run<5>(x, logw, out, w, b);
    else if (o == 6) duh_run<6>(x, logw, out, w, b);
    else             duh_run<7>(x, logw, out, w, b);
}

extern "C" void kernel_launch(void* const* d_in, const int* in_sizes, int n_in,
                              void* d_out, int out_size, void* d_ws, size_t ws_size,
                              hipStream_t stream) {
    const float* x  = (const float*)d_in[0];
    const float* lw = (const float*)d_in[1];
    float* out = (float*)d_out;

    // 8 ch * 16 batch * 16 blocks (4 waves each -> 64 waves per (ch,batch))
    dim3 grid(NO * NB * 16);          // 2048 blocks * 256 thr = 524,288 thr
    duh_kernel<<<grid, dim3(NT), 0, stream>>>(x, lw, out);
}

// Round 9
// 21.215 us; speedup vs baseline: 2.2635x; 2.2635x over previous
//
#include <hip/hip_runtime.h>
#include <math.h>

// Duhamel layer == per-channel causal FIR, h[q] = (1/wD) r^q sin(q*theta).
// One-stream exact form: e[k] = xs[k] - g^W xs[k-W]  (xs = x/wD, complex IIR
// Z = g Z + e, y = Im Z).  This round: ALL global reads are cooperative
// coalesced stages into one LDS tile; IIR reads s1/s2 from LDS; local y kept
// in registers; after the scan the corrected y overwrites the thread's own
// (dead) xs slots in the SAME tile; coalesced cooperative store.
// Rationale (r8 counters): per-lane segment loads touch 64 cache lines/inst
// (~1 line/cy/CU service rate) -> that, not VALU/HBM, was the limiter.

#define N_SAMP  65536
#define NB      16
#define NO      8
#define SPAN    6144
#define NT      512
#define LSEG    12

// Static FIR lengths (exact replica of reference VALID_W):
constexpr int CW[NO]   = {1844, 1317, 1024, 768, 576, 419, 307, 230};
// Halo: mult of 12 (=LSEG), >= ceil(7/alpha) (seed error e^-7 ~ 9e-4 rel).
constexpr int CH[NO]   = {2808, 2004, 1560, 1176, 876, 648, 468, 360};
// chunks = ceil(65536 / (6144-H)) per channel; prefix offsets:
constexpr int COFF[NO + 1] = {0, 20, 36, 51, 65, 78, 90, 102, 114};

// +4 floats of pad per 32 (4-aligned quads stay contiguous)
__device__ __forceinline__ int pidx4(int i) { return i + ((i >> 5) << 2); }

__device__ __forceinline__ float rfl(float x) {
    return __int_as_float(__builtin_amdgcn_readfirstlane(__float_as_int(x)));
}

template<int O>
__device__ __forceinline__ void duh_run(const float* __restrict__ xg,
                                        const float* __restrict__ logw,
                                        float* __restrict__ out,
                                        float* __restrict__ tile,
                                        float (* __restrict__ wtot)[2],
                                        int c, int b)
{
    constexpr int W    = CW[O];
    constexpr int H    = CH[O];
    constexpr int L    = SPAN - H;
    constexpr int Wpad = (W + 3) & ~3;       // quad-aligned lookback
    constexpr int E    = Wpad - W;           // 0..3 static shift
    constexpr int XW   = SPAN + Wpad;        // staged tile length
    constexpr int NQ2  = (E == 0) ? 3 : 4;   // delayed-stream quads per thread

    const int n0   = c * L;
    const int t    = threadIdx.x;
    const int lane = t & 63;
    const int wv   = t >> 6;

    // ------- per-channel constants (fast HW transcendentals) -> SGPR --------
    const float XIf = 0.05f, DTf = 0.01f;
    const float omf  = fminf(fmaxf(__expf(logw[O]), 0.01f), 1000.0f);
    const float omD  = omf * sqrtf(1.0f - XIf * XIf);
    const float th   = omD * DTf;
    const float alph = XIf * omf * DTf;

    const float r1 = __expf(-alph);
    const float gr = rfl(r1 * __cosf(th)), gi = rfl(r1 * __sinf(th));   // g

    const float rW   = __expf(-alph * (float)W);
    const float aW   = th * (float)W;
    const float binv = rfl(1.0f / omD);
    const float sWr  = rfl(rW * __cosf(aW));            // Re g^W
    const float cei  = rfl(-rW * __sinf(aW));           // -Im g^W (binv staged)

    float Mr[7], Mi[7];                                  // M[k] = g^(12*2^k)
    {
        const float rl = __expf(-alph * (float)LSEG);
        const float al = th * (float)LSEG;
        float pr = rl * __cosf(al), pq = rl * __sinf(al);
#pragma unroll
        for (int k = 0; k < 7; ++k) {
            Mr[k] = rfl(pr); Mi[k] = rfl(pq);
            const float nr = pr * pr - pq * pq;
            const float ni = 2.0f * pr * pq;
            pr = nr; pq = ni;
        }
    }

    // ---------------- coalesced co-op stage: xs = binv*x into tile ----------
    const int xbase = n0 - H - Wpad;                     // global idx of tile[0]
    const float* xb = xg + (size_t)b * N_SAMP;
    for (int k = 4 * t; k < XW; k += 4 * NT) {
        const int g0 = xbase + k;                        // mult of 4
        float4 v;
        if (g0 >= 0 && g0 + 3 < N_SAMP) {
            v = *(const float4*)(xb + g0);
        } else {
            v.x = (g0 + 0 >= 0 && g0 + 0 < N_SAMP) ? xb[g0 + 0] : 0.0f;
            v.y = (g0 + 1 >= 0 && g0 + 1 < N_SAMP) ? xb[g0 + 1] : 0.0f;
            v.z = (g0 + 2 >= 0 && g0 + 2 < N_SAMP) ? xb[g0 + 2] : 0.0f;
            v.w = (g0 + 3 >= 0 && g0 + 3 < N_SAMP) ? xb[g0 + 3] : 0.0f;
        }
        v.x *= binv; v.y *= binv; v.z *= binv; v.w *= binv;
        *(float4*)&tile[pidx4(k)] = v;
    }
    __syncthreads();

    // ---------------- phase A: LDS reads + IIR, ly in registers -------------
    // thread t owns tile-logical samples [Wpad+12t, Wpad+12t+12)
    // delayed sample j lives at tile-logical 12t + E + j
    float s1raw[12];
#pragma unroll
    for (int m = 0; m < 3; ++m) {
        const float4 q = *(const float4*)&tile[pidx4(Wpad + 12 * t + 4 * m)];
        s1raw[4*m+0] = q.x; s1raw[4*m+1] = q.y; s1raw[4*m+2] = q.z; s1raw[4*m+3] = q.w;
    }
    float s2raw[4 * NQ2];
#pragma unroll
    for (int m = 0; m < NQ2; ++m) {
        const float4 q = *(const float4*)&tile[pidx4(12 * t + 4 * m)];
        s2raw[4*m+0] = q.x; s2raw[4*m+1] = q.y; s2raw[4*m+2] = q.z; s2raw[4*m+3] = q.w;
    }

    float ly[LSEG];
    float Br = 0.f, Bi = 0.f;
#pragma unroll
    for (int j = 0; j < LSEG; ++j) {
        const float a  = s1raw[j];
        const float cc = s2raw[E + j];
        const float er = fmaf(-sWr, cc, a);              // Re e
        const float ei = cei * cc;                       // Im e
        const float nr = fmaf(gr, Br, fmaf(-gi, Bi, er));
        const float ni = fmaf(gi, Br, fmaf( gr, Bi, ei));
        Br = nr; Bi = ni;
        ly[j] = Bi;
    }

    // ---------------- wave-level inclusive affine scan ----------------------
    float Sr = Br, Si = Bi;
#pragma unroll
    for (int k = 0; k < 6; ++k) {
        const int d = 1 << k;
        const float ur = __shfl_up(Sr, d, 64);
        const float ui = __shfl_up(Si, d, 64);
        if (lane >= d) {
            const float nr = fmaf(Mr[k], ur, fmaf(-Mi[k], ui, Sr));
            const float ni = fmaf(Mr[k], ui, fmaf( Mi[k], ur, Si));
            Sr = nr; Si = ni;
        }
    }
    if (lane == 63) { wtot[wv][0] = Sr; wtot[wv][1] = Si; }
    __syncthreads();

    // cross-wave carry (multiplier g^768 = M[6])
    float cr = 0.f, ci = 0.f;
    for (int w2 = 0; w2 < wv; ++w2) {
        const float tr = wtot[w2][0], ti = wtot[w2][1];
        const float nr = fmaf(Mr[6], cr, fmaf(-Mi[6], ci, tr));
        const float ni = fmaf(Mr[6], ci, fmaf( Mi[6], cr, ti));
        cr = nr; ci = ni;
    }

    // exclusive in-wave prefix
    float pr_ = __shfl_up(Sr, 1, 64);
    float pi_ = __shfl_up(Si, 1, 64);
    if (lane == 0) { pr_ = 0.f; pi_ = 0.f; }

    // m^lane (product over set bits of lane)
    float plr = 1.f, pli = 0.f;
#pragma unroll
    for (int k = 0; k < 6; ++k) {
        if ((lane >> k) & 1) {
            const float nr = plr * Mr[k] - pli * Mi[k];
            const float ni = plr * Mi[k] + pli * Mr[k];
            plr = nr; pli = ni;
        }
    }
    // exact seed entering this thread's segment: u = pl*carry + excl
    const float ur_ = fmaf(plr, cr, fmaf(-pli, ci, pr_));
    const float ui_ = fmaf(plr, ci, fmaf( pli, cr, pi_));

    // -------- phase B: correct in registers, overwrite OWN tile slots -------
    {
        float vr = fmaf(gr, ur_, -(gi * ui_));           // v = g*u
        float vi = fmaf(gi, ur_,  (gr * ui_));
#pragma unroll
        for (int j = 0; j < LSEG; ++j) {
            ly[j] += vi;                                 // y = ly + Im(g^{j+1} u)
            const float nr = fmaf(gr, vr, -(gi * vi));
            const float ni = fmaf(gi, vr,  (gr * vi));
            vr = nr; vi = ni;
        }
#pragma unroll
        for (int m = 0; m < 3; ++m) {
            float4 q;
            q.x = ly[4*m+0]; q.y = ly[4*m+1]; q.z = ly[4*m+2]; q.w = ly[4*m+3];
            *(float4*)&tile[pidx4(Wpad + 12 * t + 4 * m)] = q;  // own slots
        }
    }
    __syncthreads();

    // ---------------- coalesced co-op store: y = tile[Wpad+H ..] ------------
    const int kmax = (n0 + L <= N_SAMP) ? L : (N_SAMP - n0);
    float* op = out + ((size_t)(b * NO + O)) * (size_t)N_SAMP + n0;
    for (int k = 4 * t; k < kmax; k += 4 * NT) {
        const float4 v = *(const float4*)&tile[pidx4(Wpad + H + k)];
        *(float4*)(op + k) = v;
    }
}

__global__ __launch_bounds__(NT, 8)
void duh_kernel(const float* __restrict__ x, const float* __restrict__ logw,
                float* __restrict__ out)
{
    extern __shared__ float tile[];
    __shared__ float wtot[8][2];
    const int cid = blockIdx.x;
    const int b   = blockIdx.y;
    if      (cid < COFF[1]) duh_run<0>(x, logw, out, tile, wtot, cid - COFF[0], b);
    else if (cid < COFF[2]) duh_run<1>(x, logw, out, tile, wtot, cid - COFF[1], b);
    else if (cid < COFF[3]) duh_run<2>(x, logw, out, tile, wtot, cid - COFF[2], b);
    else if (cid < COFF[4]) duh_run<3>(x, logw, out, tile, wtot, cid - COFF[3], b);
    else if (cid < COFF[5]) duh_run<4>(x, logw, out, tile, wtot, cid - COFF[4], b);
    else if (cid < COFF[6]) duh_run<5>(x, logw, out, tile, wtot, cid - COFF[5], b);
    else if (cid < COFF[7]) duh_run<6>(x, logw, out, tile, wtot, cid - COFF[6], b);
    else                    duh_run<7>(x, logw, out, tile, wtot, cid - COFF[7], b);
}

extern "C" void kernel_launch(void* const* d_in, const int* in_sizes, int n_in,
                              void* d_out, int out_size, void* d_ws, size_t ws_size,
                              hipStream_t stream) {
    const float* x  = (const float*)d_in[0];
    const float* lw = (const float*)d_in[1];
    float* out = (float*)d_out;

    // dynamic tile sized for largest channel (O=0): XW = 6144+1844 = 7988
    // padded words = 7988 + 4*(7988/32) = 8984 -> 35,936 bytes
    const size_t lds_bytes = (size_t)(7988 + 4 * (7988 / 32)) * sizeof(float);

    dim3 grid(COFF[NO], NB);   // 114 chunk-slots x 16 batches = 1824 blocks
    duh_kernel<<<grid, dim3(NT), lds_bytes, stream>>>(x, lw, out);
}